// Round 6
// baseline (538.375 us; speedup 1.0000x reference)
//
#include <hip/hip_runtime.h>
#include <cstdint>
#include <cstddef>

typedef __attribute__((ext_vector_type(4))) float  f32x4;
typedef __attribute__((ext_vector_type(8))) short  short8;

#define NBLK 512

__device__ __forceinline__ short f2bf(float f) {
  unsigned u = __float_as_uint(f);
  u += 0x7FFF + ((u >> 16) & 1);   // round-to-nearest-even
  return (short)(u >> 16);
}
__device__ __forceinline__ float sigmoidf(float x) {
  return 1.0f / (1.0f + __expf(-x));
}

// device-scope grid barrier; one slot per sync point, zeroed each launch
__device__ __forceinline__ void grid_sync(int* bar, int idx) {
  __syncthreads();
  if (threadIdx.x == 0) {
    __threadfence();
    __hip_atomic_fetch_add(bar + idx, 1, __ATOMIC_RELEASE, __HIP_MEMORY_SCOPE_AGENT);
    while (__hip_atomic_load(bar + idx, __ATOMIC_ACQUIRE, __HIP_MEMORY_SCOPE_AGENT) < NBLK)
      __builtin_amdgcn_s_sleep(1);
    __threadfence();
  }
  __syncthreads();
}

// per-wave GEMM chunk: 4 m-frags x 16 n-cols x NK 32-k steps, 1-deep prefetch.
// B (weights) loaded non-temporally; A (bf16 activations) cached.
template<int K, int NK>
__device__ __forceinline__ void gemm_chunk(const short* __restrict__ Ap,
                                           const float* __restrict__ Bp,
                                           f32x4& acc0, f32x4& acc1,
                                           f32x4& acc2, f32x4& acc3) {
  f32x4 bc0 = __builtin_nontemporal_load((const f32x4*)Bp);
  f32x4 bc1 = __builtin_nontemporal_load((const f32x4*)(Bp + 4));
  short8 ac0 = *(const short8*)(Ap);
  short8 ac1 = *(const short8*)(Ap + 16 * K);
  short8 ac2 = *(const short8*)(Ap + 32 * K);
  short8 ac3 = *(const short8*)(Ap + 48 * K);
  for (int t = 0; t < NK; ++t) {
    f32x4 bn0 = {}, bn1 = {};
    short8 an0 = {}, an1 = {}, an2 = {}, an3 = {};
    if (t + 1 < NK) {
      const float* bp = Bp + (t + 1) * 32;
      const short* ap = Ap + (t + 1) * 32;
      bn0 = __builtin_nontemporal_load((const f32x4*)bp);
      bn1 = __builtin_nontemporal_load((const f32x4*)(bp + 4));
      an0 = *(const short8*)(ap);
      an1 = *(const short8*)(ap + 16 * K);
      an2 = *(const short8*)(ap + 32 * K);
      an3 = *(const short8*)(ap + 48 * K);
    }
    short8 bb;
    bb[0] = f2bf(bc0[0]); bb[1] = f2bf(bc0[1]); bb[2] = f2bf(bc0[2]); bb[3] = f2bf(bc0[3]);
    bb[4] = f2bf(bc1[0]); bb[5] = f2bf(bc1[1]); bb[6] = f2bf(bc1[2]); bb[7] = f2bf(bc1[3]);
    acc0 = __builtin_amdgcn_mfma_f32_16x16x32_bf16(ac0, bb, acc0, 0, 0, 0);
    acc1 = __builtin_amdgcn_mfma_f32_16x16x32_bf16(ac1, bb, acc1, 0, 0, 0);
    acc2 = __builtin_amdgcn_mfma_f32_16x16x32_bf16(ac2, bb, acc2, 0, 0, 0);
    acc3 = __builtin_amdgcn_mfma_f32_16x16x32_bf16(ac3, bb, acc3, 0, 0, 0);
    bc0 = bn0; bc1 = bn1;
    ac0 = an0; ac1 = an1; ac2 = an2; ac3 = an3;
  }
}

// write wave's C/D frags to LDS: m = frag*16 + (l>>4)*4 + r, n = l&15
__device__ __forceinline__ void store_frag(float* rw, int l,
    const f32x4& a0, const f32x4& a1, const f32x4& a2, const f32x4& a3) {
  const int mb = (l >> 4) << 2;
  const int nn = l & 15;
#pragma unroll
  for (int r = 0; r < 4; ++r) rw[(mb + r) * 16 + nn] = a0[r];
#pragma unroll
  for (int r = 0; r < 4; ++r) rw[(16 + mb + r) * 16 + nn] = a1[r];
#pragma unroll
  for (int r = 0; r < 4; ++r) rw[(32 + mb + r) * 16 + nn] = a2[r];
#pragma unroll
  for (int r = 0; r < 4; ++r) rw[(48 + mb + r) * 16 + nn] = a3[r];
}

__global__ __launch_bounds__(512, 4) void mega_kernel(
    const float* __restrict__ x,  const float* __restrict__ w1,
    const float* __restrict__ b1, const float* __restrict__ w2,
    const float* __restrict__ b2,
    short* __restrict__ g_bf, short* __restrict__ h_bf,
    float* __restrict__ g1p,  float* __restrict__ fpart,
    int* __restrict__ bar,
    float* __restrict__ wout, float* __restrict__ feat) {
  __shared__ float lds[8192];   // 32 KB: red[8][1024] for GEMMs, gs[1024] for einsum
  const int tid = threadIdx.x;
  const int bid = blockIdx.x;
  const int l   = tid & 63;
  const int wv  = tid >> 6;

  // ---- stage P: pool x -> g_bf (bf16). 4096 waves x 32 rows each.
  {
    const int gw = bid * 8 + wv;
    const float* base = x + (size_t)gw * 32 * 196;
    for (int r = 0; r < 32; ++r) {
      float s = 0.f;
      if (l < 49) {
        f32x4 v = *(const f32x4*)(base + r * 196 + l * 4);
        s = v[0] + v[1] + v[2] + v[3];
      }
#pragma unroll
      for (int off = 32; off > 0; off >>= 1) s += __shfl_down(s, off);
      if (l == 0) g_bf[gw * 32 + r] = f2bf(s * (1.0f / 196.0f));
    }
  }
  grid_sync(bar, 0);

  // ---- stage G1: 256 col-groups x 2 half-K blocks -> g1p partials
  {
    const int cg = bid >> 1, half = bid & 1;
    const int n0 = cg * 16;
    const int kw0 = half * 1024 + wv * 128;
    const int ko = (l >> 4) * 8;
    const float* Bp = w1 + (size_t)(n0 + (l & 15)) * 2048 + kw0 + ko;
    const short* Ap = g_bf + (size_t)(l & 15) * 2048 + kw0 + ko;
    f32x4 a0 = {}, a1 = {}, a2 = {}, a3 = {};
    gemm_chunk<2048, 4>(Ap, Bp, a0, a1, a2, a3);
    store_frag(lds + wv * 1024, l, a0, a1, a2, a3);
    __syncthreads();
#pragma unroll
    for (int i = tid; i < 1024; i += 512) {
      float s = 0.f;
#pragma unroll
      for (int w = 0; w < 8; ++w) s += lds[w * 1024 + i];
      g1p[(size_t)half * 262144 + (size_t)(i >> 4) * 4096 + n0 + (i & 15)] = s;
    }
  }
  grid_sync(bar, 1);

  // ---- stage G1R: reduce halves + bias + sigmoid -> h_bf (1 elem/thread)
  {
    const int i = bid * 512 + tid;     // 0..262143 exact
    const int n = i & 4095;
    float s = g1p[i] + g1p[262144 + i] + b1[n];
    h_bf[i] = f2bf(sigmoidf(s));
  }
  grid_sync(bar, 2);

  // ---- stage G2: 512 col-groups, full K per block -> wout (f32 final)
  {
    const int n0 = bid * 16;
    const int kw0 = wv * 512;
    const int ko = (l >> 4) * 8;
    const float* Bp = w2 + (size_t)(n0 + (l & 15)) * 4096 + kw0 + ko;
    const short* Ap = h_bf + (size_t)(l & 15) * 4096 + kw0 + ko;
    f32x4 a0 = {}, a1 = {}, a2 = {}, a3 = {};
    gemm_chunk<4096, 16>(Ap, Bp, a0, a1, a2, a3);
    store_frag(lds + wv * 1024, l, a0, a1, a2, a3);
    __syncthreads();
#pragma unroll
    for (int i = tid; i < 1024; i += 512) {
      float s = 0.f;
#pragma unroll
      for (int w = 0; w < 8; ++w) s += lds[w * 1024 + i];
      const int m = i >> 4, nn = n0 + (i & 15);
      wout[(size_t)m * 8192 + nn] = sigmoidf(s + b2[nn]);
    }
  }
  grid_sync(bar, 3);

  // ---- stage E: einsum partials. 512 blocks = 64 b x 8 cc-pairs; block
  // halves handle cc, cc+1. x re-read should hit L3 (nt kept weights out).
  {
    const int b   = bid >> 3;
    const int h2  = tid >> 8, tid2 = tid & 255;
    const int cc  = (bid & 7) * 2 + h2;
    float* gs = lds + h2 * 512;
#pragma unroll
    for (int i = 0; i < 2; ++i) {
      int idx = i * 256 + tid2;          // p*128 + c
      gs[idx] = wout[(size_t)b * 8192 + (size_t)(idx >> 7) * 2048 + cc * 128 + (idx & 127)];
    }
    __syncthreads();
    if (tid2 < 196) {
      const float* xp = x + (size_t)b * 2048 * 196 + (size_t)cc * 128 * 196 + tid2;
      float a0 = 0, a1 = 0, a2 = 0, a3 = 0;
#pragma unroll 8
      for (int c = 0; c < 128; ++c) {
        float xv = xp[(size_t)c * 196];
        a0 += gs[c]       * xv;
        a1 += gs[128 + c] * xv;
        a2 += gs[256 + c] * xv;
        a3 += gs[384 + c] * xv;
      }
      float* fp = fpart + ((size_t)(b * 16 + cc) * 4) * 196 + tid2;
      fp[0]   = a0;
      fp[196] = a1;
      fp[392] = a2;
      fp[588] = a3;
    }
  }
  grid_sync(bar, 4);

  // ---- stage FR: reduce 16 cc partials -> feat
  {
    const int i = bid * 512 + tid;
    if (i < 64 * 4 * 196) {
      const int s = i % 196;
      const int p = (i / 196) & 3;
      const int b = i / 784;
      float sum = 0.f;
#pragma unroll
      for (int cc = 0; cc < 16; ++cc)
        sum += fpart[((size_t)(b * 16 + cc) * 4 + p) * 196 + s];
      feat[i] = sum * (1.0f / 2048.0f);
    }
  }
}

extern "C" void kernel_launch(void* const* d_in, const int* in_sizes, int n_in,
                              void* d_out, int out_size, void* d_ws, size_t ws_size,
                              hipStream_t stream) {
  const float* x  = (const float*)d_in[0];   // [64,2048,14,14]
  const float* w1 = (const float*)d_in[1];   // [4096,2048]
  const float* b1 = (const float*)d_in[2];   // [4096]
  const float* w2 = (const float*)d_in[3];   // [8192,4096]
  const float* b2 = (const float*)d_in[4];   // [8192]
  float* out = (float*)d_out;

  char* ws = (char*)d_ws;
  int*   bar   = (int*)ws;                       // 5 slots (zeroed each launch)
  short* g_bf  = (short*)(ws + 4096);            // 64*2048 bf16, 256 KB
  short* h_bf  = (short*)(ws + 524288);          // 64*4096 bf16, 512 KB
  float* g1p   = (float*)(ws + 1048576);         // 2 * 64*4096 f32, 2 MB
  float* fpart = (float*)(ws + 3145728);         // 64*16*4*196 f32, 3.2 MB

  float* wout = out;                             // [64, 8192] == [B,P,C]
  float* feat = out + 524288;                    // [64, 4, 196]

  hipMemsetAsync(bar, 0, 4096, stream);          // reset barrier slots
  mega_kernel<<<NBLK, 512, 0, stream>>>(x, w1, b1, w2, b2,
                                        g_bf, h_bf, g1p, fpart, bar, wout, feat);
}

// Round 7
// 112.330 us; speedup vs baseline: 4.7928x; 4.7928x over previous
//
#include <hip/hip_runtime.h>
#include <cstdint>
#include <cstddef>

typedef __attribute__((ext_vector_type(4))) float  f32x4;
typedef __attribute__((ext_vector_type(8))) short  short8;

__device__ __forceinline__ short f2bf(float f) {
  unsigned u = __float_as_uint(f);
  u += 0x7FFF + ((u >> 16) & 1);   // round-to-nearest-even
  return (short)(u >> 16);
}
__device__ __forceinline__ float sigmoidf(float x) {
  return 1.0f / (1.0f + __expf(-x));
}

// ---------------- pool: g[b,c] = mean_s x[b,c,s] -> bf16 --------------------
// one wave per row (row = (b,c) pair), 4 rows per 256-thread block
__global__ __launch_bounds__(256) void pool_kernel(const float* __restrict__ x,
                                                   short* __restrict__ g,
                                                   int nrows) {
  int gid  = blockIdx.x * 256 + threadIdx.x;
  int row  = gid >> 6;
  int lane = threadIdx.x & 63;
  if (row >= nrows) return;
  float s = 0.f;
  if (lane < 49) {                       // 196 floats = 49 float4
    const float4* p = (const float4*)(x + (size_t)row * 196);
    float4 v = p[lane];
    s = v.x + v.y + v.z + v.w;
  }
#pragma unroll
  for (int off = 32; off > 0; off >>= 1) s += __shfl_down(s, off);
  if (lane == 0) g[row] = f2bf(s * (1.0f / 196.0f));
}

// --------- barrier-free GEMM: out[m,n] = act(sum_k A[m,k]*B[n,k] + bias) ----
// A: [64][K] bf16 (L2-resident, cached), B: [N][K] f32 streamed with
// NON-TEMPORAL loads (single-use; keeps x resident in L3).
// Block = 512 threads = 8 waves; block owns 16 n-columns; K split 8-way
// across waves; LDS reduce + bias + sigmoid epilogue. No HBM partials.
template<int N, int K, bool OUT_BF16>
__global__ __launch_bounds__(512, 4) void gemm_fused(const short* __restrict__ A,
                                                     const float* __restrict__ B,
                                                     const float* __restrict__ bias,
                                                     void* __restrict__ outp) {
  constexpr int KW = K / 8;        // k-range per wave
  constexpr int NK = KW / 32;      // MFMA k-steps per wave
  const int n0  = blockIdx.x * 16;
  const int tid = threadIdx.x;
  const int l   = tid & 63;
  const int wv  = tid >> 6;
  const int kw0 = wv * KW;

  __shared__ float red[8 * 1024];  // [wave][m*16+n] f32

  const int ko = (l >> 4) * 8;     // k-offset within 32-k step (operand layout)
  const float* Bp = B + (size_t)(n0 + (l & 15)) * K + kw0 + ko;
  const short* Ap = A + (size_t)(l & 15) * K + kw0 + ko;

  f32x4 acc0 = {}, acc1 = {}, acc2 = {}, acc3 = {};

  // prefetch t=0  (B non-temporal)
  f32x4 bc0 = __builtin_nontemporal_load((const f32x4*)Bp);
  f32x4 bc1 = __builtin_nontemporal_load((const f32x4*)(Bp + 4));
  short8 ac0 = *(const short8*)(Ap);
  short8 ac1 = *(const short8*)(Ap + 16 * K);
  short8 ac2 = *(const short8*)(Ap + 32 * K);
  short8 ac3 = *(const short8*)(Ap + 48 * K);

  for (int t = 0; t < NK; ++t) {
    f32x4 bn0 = {}, bn1 = {};
    short8 an0 = {}, an1 = {}, an2 = {}, an3 = {};
    if (t + 1 < NK) {              // issue next k-step loads early
      const float* bp = Bp + (t + 1) * 32;
      const short* ap = Ap + (t + 1) * 32;
      bn0 = __builtin_nontemporal_load((const f32x4*)bp);
      bn1 = __builtin_nontemporal_load((const f32x4*)(bp + 4));
      an0 = *(const short8*)(ap);
      an1 = *(const short8*)(ap + 16 * K);
      an2 = *(const short8*)(ap + 32 * K);
      an3 = *(const short8*)(ap + 48 * K);
    }
    short8 bb;
    bb[0] = f2bf(bc0[0]); bb[1] = f2bf(bc0[1]); bb[2] = f2bf(bc0[2]); bb[3] = f2bf(bc0[3]);
    bb[4] = f2bf(bc1[0]); bb[5] = f2bf(bc1[1]); bb[6] = f2bf(bc1[2]); bb[7] = f2bf(bc1[3]);
    acc0 = __builtin_amdgcn_mfma_f32_16x16x32_bf16(ac0, bb, acc0, 0, 0, 0);
    acc1 = __builtin_amdgcn_mfma_f32_16x16x32_bf16(ac1, bb, acc1, 0, 0, 0);
    acc2 = __builtin_amdgcn_mfma_f32_16x16x32_bf16(ac2, bb, acc2, 0, 0, 0);
    acc3 = __builtin_amdgcn_mfma_f32_16x16x32_bf16(ac3, bb, acc3, 0, 0, 0);
    bc0 = bn0; bc1 = bn1;
    ac0 = an0; ac1 = an1; ac2 = an2; ac3 = an3;
  }

  // wave-partial -> LDS (C/D layout: m = mi*16 + (l>>4)*4 + r, n = l&15)
  {
    float* rw = red + wv * 1024;
    const int mb = (l >> 4) << 2;
    const int nn = l & 15;
#pragma unroll
    for (int r = 0; r < 4; ++r) rw[(0  + mb + r) * 16 + nn] = acc0[r];
#pragma unroll
    for (int r = 0; r < 4; ++r) rw[(16 + mb + r) * 16 + nn] = acc1[r];
#pragma unroll
    for (int r = 0; r < 4; ++r) rw[(32 + mb + r) * 16 + nn] = acc2[r];
#pragma unroll
    for (int r = 0; r < 4; ++r) rw[(48 + mb + r) * 16 + nn] = acc3[r];
  }
  __syncthreads();

  // reduce 8 wave-partials + bias + sigmoid, write final
#pragma unroll
  for (int i = tid; i < 1024; i += 512) {
    float s = 0.f;
#pragma unroll
    for (int w = 0; w < 8; ++w) s += red[w * 1024 + i];
    int m  = i >> 4;
    int nn = n0 + (i & 15);
    s = sigmoidf(s + bias[nn]);
    if constexpr (OUT_BF16) ((short*)outp)[(size_t)m * N + nn] = f2bf(s);
    else                    ((float*)outp)[(size_t)m * N + nn] = s;
  }
}

// --------- einsum partials: fpart[(b*16+cc)*4+p][s] = sum_{c in chunk} w*x --
__global__ __launch_bounds__(256) void einsum_part(const float* __restrict__ x,
                                                   const float* __restrict__ wg,
                                                   float* __restrict__ fpart) {
  const int b  = blockIdx.x >> 4;
  const int cc = blockIdx.x & 15;
  __shared__ float gs[4 * 128];
  const int tid = threadIdx.x;
  const float* wb = wg + (size_t)b * 8192 + cc * 128;
#pragma unroll
  for (int i = 0; i < 2; ++i) {
    int idx = i * 256 + tid;              // p*128 + c
    int p = idx >> 7, c = idx & 127;
    gs[idx] = wb[p * 2048 + c];
  }
  __syncthreads();
  if (tid < 196) {
    const float* xp = x + (size_t)b * 2048 * 196 + (size_t)cc * 128 * 196 + tid;
    float a0 = 0, a1 = 0, a2 = 0, a3 = 0;
#pragma unroll 8
    for (int c = 0; c < 128; ++c) {
      float xv = xp[(size_t)c * 196];
      a0 += gs[c]       * xv;
      a1 += gs[128 + c] * xv;
      a2 += gs[256 + c] * xv;
      a3 += gs[384 + c] * xv;
    }
    float* fp = fpart + ((size_t)(b * 16 + cc) * 4) * 196 + tid;
    fp[0]   = a0;
    fp[196] = a1;
    fp[392] = a2;
    fp[588] = a3;
  }
}

// --------- reduce einsum c-chunk partials, scale by 1/C ---------------------
__global__ __launch_bounds__(256) void feat_reduce(const float* __restrict__ fpart,
                                                   float* __restrict__ feat) {
  int i = blockIdx.x * 256 + threadIdx.x;   // 64*4*196 = 50176 elems
  if (i >= 64 * 4 * 196) return;
  int s = i % 196;
  int p = (i / 196) & 3;
  int b = i / 784;
  float sum = 0.f;
#pragma unroll
  for (int cc = 0; cc < 16; ++cc)
    sum += fpart[((size_t)(b * 16 + cc) * 4 + p) * 196 + s];
  feat[i] = sum * (1.0f / 2048.0f);
}

extern "C" void kernel_launch(void* const* d_in, const int* in_sizes, int n_in,
                              void* d_out, int out_size, void* d_ws, size_t ws_size,
                              hipStream_t stream) {
  const float* x  = (const float*)d_in[0];   // [64,2048,14,14]
  const float* w1 = (const float*)d_in[1];   // [4096,2048]
  const float* b1 = (const float*)d_in[2];   // [4096]
  const float* w2 = (const float*)d_in[3];   // [8192,4096]
  const float* b2 = (const float*)d_in[4];   // [8192]
  float* out = (float*)d_out;

  short* g_bf  = (short*)d_ws;                         // 64*2048 bf16 (256 KB)
  short* h_bf  = g_bf + 64 * 2048;                     // 64*4096 bf16 (512 KB)
  float* fpart = (float*)((char*)d_ws + (1 << 20));    // 64*16*4*196 f32 (3.2 MB)

  float* wout = out;                         // [64, 8192] == [B,P,C] flat
  float* feat = out + 524288;                // [64, 4, 196]

  // 1) pool -> g (bf16): 131072 rows, 4 rows/block -> 32768 blocks
  pool_kernel<<<(64 * 2048) / 4, 256, 0, stream>>>(x, g_bf, 64 * 2048);

  // 2) GEMM1: h = sigmoid(g @ w1^T + b1), bf16 out  (256 blocks x 8 waves)
  gemm_fused<4096, 2048, true><<<4096 / 16, 512, 0, stream>>>(g_bf, w1, b1, h_bf);

  // 3) GEMM2: w = sigmoid(h @ w2^T + b2), f32 out   (512 blocks x 8 waves)
  gemm_fused<8192, 4096, false><<<8192 / 16, 512, 0, stream>>>(h_bf, w2, b2, wout);

  // 4) einsum partials (64 b x 16 c-chunks)
  einsum_part<<<64 * 16, 256, 0, stream>>>(x, wout, fpart);

  // 5) reduce -> feat
  feat_reduce<<<(50176 + 255) / 256, 256, 0, stream>>>(fpart, feat);
}

// Round 8
// 103.823 us; speedup vs baseline: 5.1855x; 1.0819x over previous
//
#include <hip/hip_runtime.h>
#include <cstdint>
#include <cstddef>

typedef __attribute__((ext_vector_type(4))) float  f32x4;
typedef __attribute__((ext_vector_type(8))) short  short8;

__device__ __forceinline__ short f2bf(float f) {
  unsigned u = __float_as_uint(f);
  u += 0x7FFF + ((u >> 16) & 1);   // round-to-nearest-even
  return (short)(u >> 16);
}
__device__ __forceinline__ float sigmoidf(float x) {
  return 1.0f / (1.0f + __expf(-x));
}

// ---------------- pool: g[b,c] = mean_s x[b,c,s] -> bf16 --------------------
// one wave per row (row = (b,c) pair), 4 rows per 256-thread block
__global__ __launch_bounds__(256) void pool_kernel(const float* __restrict__ x,
                                                   short* __restrict__ g,
                                                   int nrows) {
  int gid  = blockIdx.x * 256 + threadIdx.x;
  int row  = gid >> 6;
  int lane = threadIdx.x & 63;
  if (row >= nrows) return;
  float s = 0.f;
  if (lane < 49) {                       // 196 floats = 49 float4
    const float4* p = (const float4*)(x + (size_t)row * 196);
    float4 v = p[lane];
    s = v.x + v.y + v.z + v.w;
  }
#pragma unroll
  for (int off = 32; off > 0; off >>= 1) s += __shfl_down(s, off);
  if (lane == 0) g[row] = f2bf(s * (1.0f / 196.0f));
}

// --------- barrier-free GEMM: out[m,n] = act(sum_k A[m,k]*B[n,k] + bias) ----
// A: [64][K] bf16 (L2-resident, cached), B: [N][K] f32 streamed (L2 path).
// Block = 512 threads = 8 waves; block owns 16 n-columns; K split 8-way
// across waves; LDS reduce + bias + sigmoid epilogue. No HBM partials.
// ZERO_FEAT: blocks also zero zbuf (98 floats each) for the later atomics.
template<int N, int K, bool OUT_BF16, bool ZERO_FEAT>
__global__ __launch_bounds__(512, 4) void gemm_fused(const short* __restrict__ A,
                                                     const float* __restrict__ B,
                                                     const float* __restrict__ bias,
                                                     void* __restrict__ outp,
                                                     float* __restrict__ zbuf) {
  constexpr int KW = K / 8;        // k-range per wave
  constexpr int NK = KW / 32;      // MFMA k-steps per wave
  const int n0  = blockIdx.x * 16;
  const int tid = threadIdx.x;
  const int l   = tid & 63;
  const int wv  = tid >> 6;
  const int kw0 = wv * KW;

  if constexpr (ZERO_FEAT) {       // 512 blocks x 98 = 50176 floats
    if (tid < 98) zbuf[blockIdx.x * 98 + tid] = 0.f;
  }

  __shared__ float red[8 * 1024];  // [wave][m*16+n] f32

  const int ko = (l >> 4) * 8;     // k-offset within 32-k step (operand layout)
  const float* Bp = B + (size_t)(n0 + (l & 15)) * K + kw0 + ko;
  const short* Ap = A + (size_t)(l & 15) * K + kw0 + ko;

  f32x4 acc0 = {}, acc1 = {}, acc2 = {}, acc3 = {};

  // prefetch t=0
  f32x4 bc0 = *(const f32x4*)(Bp);
  f32x4 bc1 = *(const f32x4*)(Bp + 4);
  short8 ac0 = *(const short8*)(Ap);
  short8 ac1 = *(const short8*)(Ap + 16 * K);
  short8 ac2 = *(const short8*)(Ap + 32 * K);
  short8 ac3 = *(const short8*)(Ap + 48 * K);

  for (int t = 0; t < NK; ++t) {
    f32x4 bn0 = {}, bn1 = {};
    short8 an0 = {}, an1 = {}, an2 = {}, an3 = {};
    if (t + 1 < NK) {              // issue next k-step loads early
      const float* bp = Bp + (t + 1) * 32;
      const short* ap = Ap + (t + 1) * 32;
      bn0 = *(const f32x4*)(bp);
      bn1 = *(const f32x4*)(bp + 4);
      an0 = *(const short8*)(ap);
      an1 = *(const short8*)(ap + 16 * K);
      an2 = *(const short8*)(ap + 32 * K);
      an3 = *(const short8*)(ap + 48 * K);
    }
    short8 bb;
    bb[0] = f2bf(bc0[0]); bb[1] = f2bf(bc0[1]); bb[2] = f2bf(bc0[2]); bb[3] = f2bf(bc0[3]);
    bb[4] = f2bf(bc1[0]); bb[5] = f2bf(bc1[1]); bb[6] = f2bf(bc1[2]); bb[7] = f2bf(bc1[3]);
    acc0 = __builtin_amdgcn_mfma_f32_16x16x32_bf16(ac0, bb, acc0, 0, 0, 0);
    acc1 = __builtin_amdgcn_mfma_f32_16x16x32_bf16(ac1, bb, acc1, 0, 0, 0);
    acc2 = __builtin_amdgcn_mfma_f32_16x16x32_bf16(ac2, bb, acc2, 0, 0, 0);
    acc3 = __builtin_amdgcn_mfma_f32_16x16x32_bf16(ac3, bb, acc3, 0, 0, 0);
    bc0 = bn0; bc1 = bn1;
    ac0 = an0; ac1 = an1; ac2 = an2; ac3 = an3;
  }

  // wave-partial -> LDS (C/D layout: m = mi*16 + (l>>4)*4 + r, n = l&15)
  {
    float* rw = red + wv * 1024;
    const int mb = (l >> 4) << 2;
    const int nn = l & 15;
#pragma unroll
    for (int r = 0; r < 4; ++r) rw[(0  + mb + r) * 16 + nn] = acc0[r];
#pragma unroll
    for (int r = 0; r < 4; ++r) rw[(16 + mb + r) * 16 + nn] = acc1[r];
#pragma unroll
    for (int r = 0; r < 4; ++r) rw[(32 + mb + r) * 16 + nn] = acc2[r];
#pragma unroll
    for (int r = 0; r < 4; ++r) rw[(48 + mb + r) * 16 + nn] = acc3[r];
  }
  __syncthreads();

  // reduce 8 wave-partials + bias + sigmoid, write final
#pragma unroll
  for (int i = tid; i < 1024; i += 512) {
    float s = 0.f;
#pragma unroll
    for (int w = 0; w < 8; ++w) s += red[w * 1024 + i];
    int m  = i >> 4;
    int nn = n0 + (i & 15);
    s = sigmoidf(s + bias[nn]);
    if constexpr (OUT_BF16) ((short*)outp)[(size_t)m * N + nn] = f2bf(s);
    else                    ((float*)outp)[(size_t)m * N + nn] = s;
  }
}

// --------- einsum: feat[b,p,s] += (1/C) sum_{c in chunk} w[b,p,c] x[b,c,s] --
// grid = 64 b x 16 c-chunks. Gate values read at loop-uniform addresses ->
// scalar (SGPR) loads; inner loop = 1 vector load + 4 v_fmac(v,s,v).
// feat pre-zeroed by GEMM2; 16-way atomicAdd per element.
__global__ __launch_bounds__(256) void einsum_kernel(const float* __restrict__ x,
                                                     const float* __restrict__ wg,
                                                     float* __restrict__ feat) {
  const int b   = blockIdx.x >> 4;
  const int cc  = blockIdx.x & 15;
  const int tid = threadIdx.x;
  if (tid >= 196) return;
  const float* wp = wg + (size_t)b * 8192 + cc * 128;       // + p*2048 + c (uniform)
  const float* xp = x + (size_t)b * 2048 * 196 + (size_t)cc * 128 * 196 + tid;
  float a0 = 0.f, a1 = 0.f, a2 = 0.f, a3 = 0.f;
#pragma unroll 8
  for (int c = 0; c < 128; ++c) {
    float xv = xp[(size_t)c * 196];
    a0 = __builtin_fmaf(wp[c],        xv, a0);
    a1 = __builtin_fmaf(wp[2048 + c], xv, a1);
    a2 = __builtin_fmaf(wp[4096 + c], xv, a2);
    a3 = __builtin_fmaf(wp[6144 + c], xv, a3);
  }
  const float invC = 1.0f / 2048.0f;
  atomicAdd(feat + (b * 4 + 0) * 196 + tid, a0 * invC);
  atomicAdd(feat + (b * 4 + 1) * 196 + tid, a1 * invC);
  atomicAdd(feat + (b * 4 + 2) * 196 + tid, a2 * invC);
  atomicAdd(feat + (b * 4 + 3) * 196 + tid, a3 * invC);
}

extern "C" void kernel_launch(void* const* d_in, const int* in_sizes, int n_in,
                              void* d_out, int out_size, void* d_ws, size_t ws_size,
                              hipStream_t stream) {
  const float* x  = (const float*)d_in[0];   // [64,2048,14,14]
  const float* w1 = (const float*)d_in[1];   // [4096,2048]
  const float* b1 = (const float*)d_in[2];   // [4096]
  const float* w2 = (const float*)d_in[3];   // [8192,4096]
  const float* b2 = (const float*)d_in[4];   // [8192]
  float* out = (float*)d_out;

  short* g_bf = (short*)d_ws;                // 64*2048 bf16 (256 KB)
  short* h_bf = g_bf + 64 * 2048;            // 64*4096 bf16 (512 KB)

  float* wout = out;                         // [64, 8192] == [B,P,C] flat
  float* feat = out + 524288;                // [64, 4, 196]

  // 1) pool -> g (bf16): 131072 rows, 4 rows/block
  pool_kernel<<<(64 * 2048) / 4, 256, 0, stream>>>(x, g_bf, 64 * 2048);

  // 2) GEMM1: h = sigmoid(g @ w1^T + b1), bf16 out  (256 blocks x 8 waves)
  gemm_fused<4096, 2048, true, false><<<4096 / 16, 512, 0, stream>>>(g_bf, w1, b1, h_bf, nullptr);

  // 3) GEMM2: w = sigmoid(h @ w2^T + b2), f32 out; also zeroes feat
  gemm_fused<8192, 4096, false, true><<<8192 / 16, 512, 0, stream>>>(h_bf, w2, b2, wout, feat);

  // 4) einsum -> feat (atomic accumulate over 16 c-chunks)
  einsum_kernel<<<64 * 16, 256, 0, stream>>>(x, wout, feat);
}

// Round 9
// 100.411 us; speedup vs baseline: 5.3617x; 1.0340x over previous
//
#include <hip/hip_runtime.h>
#include <cstdint>
#include <cstddef>

typedef __attribute__((ext_vector_type(4))) float  f32x4;
typedef __attribute__((ext_vector_type(8))) short  short8;

__device__ __forceinline__ short f2bf(float f) {
  unsigned u = __float_as_uint(f);
  u += 0x7FFF + ((u >> 16) & 1);   // round-to-nearest-even
  return (short)(u >> 16);
}
__device__ __forceinline__ float sigmoidf(float x) {
  return 1.0f / (1.0f + __expf(-x));
}

// ---------------- pool: g[b,c] = mean_s x[b,c,s] -> bf16 --------------------
// 16 rows per 256-thread block: 784 contiguous float4 loads (dense, full
// lines), LDS scratch, deterministic per-row 49-way sums. 8192 blocks.
__global__ __launch_bounds__(256) void pool_kernel(const float* __restrict__ x,
                                                   short* __restrict__ g) {
  __shared__ float sums[784];
  const int tid = threadIdx.x;
  const f32x4* base = (const f32x4*)(x + (size_t)blockIdx.x * (16 * 196));
#pragma unroll
  for (int it = 0; it < 4; ++it) {
    int i = it * 256 + tid;
    if (it < 3 || tid < 16) {
      f32x4 v = base[i];
      sums[i] = v[0] + v[1] + v[2] + v[3];
    }
  }
  __syncthreads();
  if (tid < 16) {
    float s = 0.f;
#pragma unroll
    for (int j = 0; j < 49; ++j) s += sums[tid * 49 + j];
    g[blockIdx.x * 16 + tid] = f2bf(s * (1.0f / 196.0f));
  }
}

// --------- barrier-free GEMM body: out = act(A @ B^T + bias) ----------------
// A: [64][K] bf16 (L2-resident, cached), B: [N][K] f32 streamed to regs.
// WAVES waves split K; LDS reduce + bias + sigmoid epilogue. No HBM partials.
template<int N, int K, int WAVES, bool OUT_BF16, bool ZERO_FEAT>
__device__ __forceinline__ void gemm_body(const short* __restrict__ A,
                                          const float* __restrict__ B,
                                          const float* __restrict__ bias,
                                          void* __restrict__ outp,
                                          float* __restrict__ zbuf,
                                          float* __restrict__ red) {
  constexpr int KW = K / WAVES;    // k-range per wave
  constexpr int NK = KW / 32;      // MFMA k-steps per wave
  constexpr int NT = WAVES * 64;   // threads
  const int n0  = blockIdx.x * 16;
  const int tid = threadIdx.x;
  const int l   = tid & 63;
  const int wv  = tid >> 6;
  const int kw0 = wv * KW;

  if constexpr (ZERO_FEAT) {       // 512 blocks x 98 = 50176 floats
    if (tid < 98) zbuf[blockIdx.x * 98 + tid] = 0.f;
  }

  const int ko = (l >> 4) * 8;     // k-offset within 32-k step (operand layout)
  const float* Bp = B + (size_t)(n0 + (l & 15)) * K + kw0 + ko;
  const short* Ap = A + (size_t)(l & 15) * K + kw0 + ko;

  f32x4 acc0 = {}, acc1 = {}, acc2 = {}, acc3 = {};

  // prefetch t=0
  f32x4 bc0 = *(const f32x4*)(Bp);
  f32x4 bc1 = *(const f32x4*)(Bp + 4);
  short8 ac0 = *(const short8*)(Ap);
  short8 ac1 = *(const short8*)(Ap + 16 * K);
  short8 ac2 = *(const short8*)(Ap + 32 * K);
  short8 ac3 = *(const short8*)(Ap + 48 * K);

  for (int t = 0; t < NK; ++t) {
    f32x4 bn0 = {}, bn1 = {};
    short8 an0 = {}, an1 = {}, an2 = {}, an3 = {};
    if (t + 1 < NK) {              // issue next k-step loads early
      const float* bp = Bp + (t + 1) * 32;
      const short* ap = Ap + (t + 1) * 32;
      bn0 = *(const f32x4*)(bp);
      bn1 = *(const f32x4*)(bp + 4);
      an0 = *(const short8*)(ap);
      an1 = *(const short8*)(ap + 16 * K);
      an2 = *(const short8*)(ap + 32 * K);
      an3 = *(const short8*)(ap + 48 * K);
    }
    short8 bb;
    bb[0] = f2bf(bc0[0]); bb[1] = f2bf(bc0[1]); bb[2] = f2bf(bc0[2]); bb[3] = f2bf(bc0[3]);
    bb[4] = f2bf(bc1[0]); bb[5] = f2bf(bc1[1]); bb[6] = f2bf(bc1[2]); bb[7] = f2bf(bc1[3]);
    acc0 = __builtin_amdgcn_mfma_f32_16x16x32_bf16(ac0, bb, acc0, 0, 0, 0);
    acc1 = __builtin_amdgcn_mfma_f32_16x16x32_bf16(ac1, bb, acc1, 0, 0, 0);
    acc2 = __builtin_amdgcn_mfma_f32_16x16x32_bf16(ac2, bb, acc2, 0, 0, 0);
    acc3 = __builtin_amdgcn_mfma_f32_16x16x32_bf16(ac3, bb, acc3, 0, 0, 0);
    bc0 = bn0; bc1 = bn1;
    ac0 = an0; ac1 = an1; ac2 = an2; ac3 = an3;
  }

  // wave-partial -> LDS (C/D layout: m = mi*16 + (l>>4)*4 + r, n = l&15)
  {
    float* rw = red + wv * 1024;
    const int mb = (l >> 4) << 2;
    const int nn = l & 15;
#pragma unroll
    for (int r = 0; r < 4; ++r) rw[(0  + mb + r) * 16 + nn] = acc0[r];
#pragma unroll
    for (int r = 0; r < 4; ++r) rw[(16 + mb + r) * 16 + nn] = acc1[r];
#pragma unroll
    for (int r = 0; r < 4; ++r) rw[(32 + mb + r) * 16 + nn] = acc2[r];
#pragma unroll
    for (int r = 0; r < 4; ++r) rw[(48 + mb + r) * 16 + nn] = acc3[r];
  }
  __syncthreads();

  // reduce WAVES wave-partials + bias + sigmoid, write final
#pragma unroll
  for (int i = tid; i < 1024; i += NT) {
    float s = 0.f;
#pragma unroll
    for (int w = 0; w < WAVES; ++w) s += red[w * 1024 + i];
    int m  = i >> 4;
    int nn = n0 + (i & 15);
    s = sigmoidf(s + bias[nn]);
    if constexpr (OUT_BF16) ((short*)outp)[(size_t)m * N + nn] = f2bf(s);
    else                    ((float*)outp)[(size_t)m * N + nn] = s;
  }
}

// GEMM1: 16 waves (1024 threads), 256 blocks -> 16 waves/CU
__global__ __launch_bounds__(1024, 4) void gemm1_kernel(const short* __restrict__ A,
                                                        const float* __restrict__ B,
                                                        const float* __restrict__ bias,
                                                        short* __restrict__ outp) {
  __shared__ float red[16 * 1024];
  gemm_body<4096, 2048, 16, true, false>(A, B, bias, outp, nullptr, red);
}

// GEMM2: 8 waves (512 threads), 512 blocks -> 2 blocks/CU; also zeroes feat
__global__ __launch_bounds__(512, 4) void gemm2_kernel(const short* __restrict__ A,
                                                       const float* __restrict__ B,
                                                       const float* __restrict__ bias,
                                                       float* __restrict__ outp,
                                                       float* __restrict__ zbuf) {
  __shared__ float red[8 * 1024];
  gemm_body<8192, 4096, 8, false, true>(A, B, bias, outp, zbuf, red);
}

// --------- einsum: feat[b,p,s] += (1/C) sum_{c in chunk} w[b,p,c] x[b,c,s] --
// grid = 64 b x 16 c-chunks. Gate values read at loop-uniform addresses ->
// scalar (SGPR) loads; inner loop = 1 vector load + 4 v_fmac(v,s,v).
// feat pre-zeroed by GEMM2; 16-way atomicAdd per element.
__global__ __launch_bounds__(256) void einsum_kernel(const float* __restrict__ x,
                                                     const float* __restrict__ wg,
                                                     float* __restrict__ feat) {
  const int b   = blockIdx.x >> 4;
  const int cc  = blockIdx.x & 15;
  const int tid = threadIdx.x;
  if (tid >= 196) return;
  const float* wp = wg + (size_t)b * 8192 + cc * 128;       // + p*2048 + c (uniform)
  const float* xp = x + (size_t)b * 2048 * 196 + (size_t)cc * 128 * 196 + tid;
  float a0 = 0.f, a1 = 0.f, a2 = 0.f, a3 = 0.f;
#pragma unroll 8
  for (int c = 0; c < 128; ++c) {
    float xv = xp[(size_t)c * 196];
    a0 = __builtin_fmaf(wp[c],        xv, a0);
    a1 = __builtin_fmaf(wp[2048 + c], xv, a1);
    a2 = __builtin_fmaf(wp[4096 + c], xv, a2);
    a3 = __builtin_fmaf(wp[6144 + c], xv, a3);
  }
  const float invC = 1.0f / 2048.0f;
  atomicAdd(feat + (b * 4 + 0) * 196 + tid, a0 * invC);
  atomicAdd(feat + (b * 4 + 1) * 196 + tid, a1 * invC);
  atomicAdd(feat + (b * 4 + 2) * 196 + tid, a2 * invC);
  atomicAdd(feat + (b * 4 + 3) * 196 + tid, a3 * invC);
}

extern "C" void kernel_launch(void* const* d_in, const int* in_sizes, int n_in,
                              void* d_out, int out_size, void* d_ws, size_t ws_size,
                              hipStream_t stream) {
  const float* x  = (const float*)d_in[0];   // [64,2048,14,14]
  const float* w1 = (const float*)d_in[1];   // [4096,2048]
  const float* b1 = (const float*)d_in[2];   // [4096]
  const float* w2 = (const float*)d_in[3];   // [8192,4096]
  const float* b2 = (const float*)d_in[4];   // [8192]
  float* out = (float*)d_out;

  short* g_bf = (short*)d_ws;                // 64*2048 bf16 (256 KB)
  short* h_bf = g_bf + 64 * 2048;            // 64*4096 bf16 (512 KB)

  float* wout = out;                         // [64, 8192] == [B,P,C] flat
  float* feat = out + 524288;                // [64, 4, 196]

  // 1) pool -> g (bf16): 8192 blocks x 16 rows
  pool_kernel<<<8192, 256, 0, stream>>>(x, g_bf);

  // 2) GEMM1: h = sigmoid(g @ w1^T + b1), bf16 out (256 blocks x 16 waves)
  gemm1_kernel<<<4096 / 16, 1024, 0, stream>>>(g_bf, w1, b1, h_bf);

  // 3) GEMM2: w = sigmoid(h @ w2^T + b2), f32 out; also zeroes feat
  gemm2_kernel<<<8192 / 16, 512, 0, stream>>>(h_bf, w2, b2, wout, feat);

  // 4) einsum -> feat (atomic accumulate over 16 c-chunks)
  einsum_kernel<<<64 * 16, 256, 0, stream>>>(x, wout, feat);
}